// Round 1
// baseline (1148.268 us; speedup 1.0000x reference)
//
#include <hip/hip_runtime.h>

#define T_TOKENS 8192
#define DM 1024
#define DFF 4096
#define NE 8
#define CAP 2560

typedef _Float16 f16x8 __attribute__((ext_vector_type(8)));
typedef _Float16 f16x4 __attribute__((ext_vector_type(4)));
typedef float f32x4 __attribute__((ext_vector_type(4)));

#define VMCNT(n) asm volatile("s_waitcnt vmcnt(" #n ")" ::: "memory")
#define LGKM0()  asm volatile("s_waitcnt lgkmcnt(0)" ::: "memory")
#define BARRIER() do { __builtin_amdgcn_s_barrier(); __builtin_amdgcn_sched_barrier(0); } while (0)

__device__ __forceinline__ void async16(const _Float16* g, _Float16* l) {
    __builtin_amdgcn_global_load_lds(
        (const __attribute__((address_space(1))) void*)g,
        (__attribute__((address_space(3))) void*)l, 16, 0, 0);
}

// ---------------- Kernel 0: fp32 -> fp16 weight convert ----------------
__global__ __launch_bounds__(256) void convert_kernel(
    const float* __restrict__ src, _Float16* __restrict__ dst, int n4)
{
    int i = blockIdx.x * blockDim.x + threadIdx.x;
    int stride = gridDim.x * blockDim.x;
    for (; i < n4; i += stride) {
        float4 v = ((const float4*)src)[i];
        f16x4 h = { (_Float16)v.x, (_Float16)v.y, (_Float16)v.z, (_Float16)v.w };
        ((f16x4*)dst)[i] = h;
    }
}

// ---------------- Kernel 1: LayerNorm + router (logits, softmax, top-2) ----------------
__global__ __launch_bounds__(256) void ln_router_kernel(
    const float* __restrict__ x, const float* __restrict__ gamma,
    const float* __restrict__ beta, const float* __restrict__ Wr,
    _Float16* __restrict__ xn16, int* __restrict__ slot_e, float* __restrict__ slot_w)
{
    int tok = blockIdx.x;
    int tid = threadIdx.x;
    int lane = tid & 63, wave = tid >> 6;
    const float* xr = x + (size_t)tok * DM + tid * 4;
    float4 xv = *(const float4*)xr;
    float s  = xv.x + xv.y + xv.z + xv.w;
    float ss = xv.x * xv.x + xv.y * xv.y + xv.z * xv.z + xv.w * xv.w;
    __shared__ float redS[4], redQ[4];
    __shared__ float l8s[4][NE];
    __shared__ float stats[2];
    #pragma unroll
    for (int o = 32; o > 0; o >>= 1) { s += __shfl_down(s, o); ss += __shfl_down(ss, o); }
    if (lane == 0) { redS[wave] = s; redQ[wave] = ss; }
    __syncthreads();
    if (tid == 0) {
        float S = redS[0] + redS[1] + redS[2] + redS[3];
        float Q = redQ[0] + redQ[1] + redQ[2] + redQ[3];
        float mu = S * (1.0f / DM);
        float var = Q * (1.0f / DM) - mu * mu;
        stats[0] = mu;
        stats[1] = rsqrtf(var + 1e-5f);
    }
    __syncthreads();
    float mu = stats[0], rstd = stats[1];
    float4 gv = *(const float4*)(gamma + tid * 4);
    float4 bv = *(const float4*)(beta + tid * 4);
    float xn0 = (xv.x - mu) * rstd * gv.x + bv.x;
    float xn1 = (xv.y - mu) * rstd * gv.y + bv.y;
    float xn2 = (xv.z - mu) * rstd * gv.z + bv.z;
    float xn3 = (xv.w - mu) * rstd * gv.w + bv.w;
    f16x4 h4 = { (_Float16)xn0, (_Float16)xn1, (_Float16)xn2, (_Float16)xn3 };
    *(f16x4*)(xn16 + (size_t)tok * DM + tid * 4) = h4;
    float l[NE];
    #pragma unroll
    for (int e = 0; e < NE; e++) {
        float4 wv = *(const float4*)(Wr + e * DM + tid * 4);
        l[e] = xn0 * wv.x + xn1 * wv.y + xn2 * wv.z + xn3 * wv.w;
    }
    #pragma unroll
    for (int e = 0; e < NE; e++) {
        #pragma unroll
        for (int o = 32; o > 0; o >>= 1) l[e] += __shfl_down(l[e], o);
    }
    if (lane == 0) {
        #pragma unroll
        for (int e = 0; e < NE; e++) l8s[wave][e] = l[e];
    }
    __syncthreads();
    if (tid == 0) {
        float lg[NE], ex[NE];
        float m = -1e30f;
        #pragma unroll
        for (int e = 0; e < NE; e++) {
            float v = l8s[0][e] + l8s[1][e] + l8s[2][e] + l8s[3][e];
            v = fminf(fmaxf(v, -10000.0f), 10000.0f);
            lg[e] = v;
            m = fmaxf(m, v);
        }
        float sum = 0.0f;
        #pragma unroll
        for (int e = 0; e < NE; e++) { ex[e] = expf(lg[e] - m); sum += ex[e]; }
        float inv = 1.0f / (sum + 1e-12f);
        int i0 = 0;
        #pragma unroll
        for (int e = 1; e < NE; e++) if (ex[e] > ex[i0]) i0 = e;
        int i1 = (i0 == 0) ? 1 : 0;
        #pragma unroll
        for (int e = 0; e < NE; e++) if (e != i0 && ex[e] > ex[i1]) i1 = e;
        slot_e[2 * tok]     = i0; slot_w[2 * tok]     = ex[i0] * inv;
        slot_e[2 * tok + 1] = i1; slot_w[2 * tok + 1] = ex[i1] * inv;
    }
}

// ------- Kernel 2: stable counting-sort routing: rank-within-expert + capacity drop -------
__global__ __launch_bounds__(1024) void route_build_kernel(
    const int* __restrict__ slot_e, const float* __restrict__ slot_w,
    int* __restrict__ row_token, float* __restrict__ row_w, int* __restrict__ n_rows)
{
    __shared__ int hist[1024][NE];
    int t = threadIdx.x;
    int cnt[NE];
    #pragma unroll
    for (int e = 0; e < NE; e++) cnt[e] = 0;
    int se[16];
    #pragma unroll
    for (int i = 0; i < 16; i++) { se[i] = slot_e[t * 16 + i]; cnt[se[i]]++; }
    #pragma unroll
    for (int e = 0; e < NE; e++) hist[t][e] = cnt[e];
    __syncthreads();
    for (int off = 1; off < 1024; off <<= 1) {
        int v[NE];
        bool has = (t >= off);
        if (has) {
            #pragma unroll
            for (int e = 0; e < NE; e++) v[e] = hist[t - off][e];
        }
        __syncthreads();
        if (has) {
            #pragma unroll
            for (int e = 0; e < NE; e++) hist[t][e] += v[e];
        }
        __syncthreads();
    }
    int run[NE];
    #pragma unroll
    for (int e = 0; e < NE; e++) run[e] = hist[t][e] - cnt[e];  // exclusive prefix
    if (t < NE) n_rows[t] = min(hist[1023][t], CAP);
    for (int i = 0; i < 16; i++) {
        int sidx = t * 16 + i;
        int e = se[i];
        int rnk = run[e]++;
        if (rnk < CAP) {
            int dest = e * CAP + rnk;
            row_token[dest] = sidx >> 1;
            row_w[dest] = slot_w[sidx];
        }
    }
}

// ------- Kernel 3: GEMM1 (gathered xn @ W12h^T), counted-vmcnt ring pipeline, fused SiLU*u ----
// block tile: 128 rows x (128 g-cols + 128 u-cols). BK=32.
// LDS: A ring-2 (distance 1), B ring-3 (distance 2). Raw s_barrier, counted vmcnt (never 0
// in steady state). XOR swizzle for 64B rows: phys slot = slot ^ ((row>>1)&3) -> each 16-lane
// quarter-wave covers all 8 16B bank-slots 2-way (conflict-free).
__global__ __launch_bounds__(256, 2) void gemm1_kernel(
    const _Float16* __restrict__ xn16, const _Float16* __restrict__ W12h,
    const int* __restrict__ n_rows, const int* __restrict__ row_token,
    _Float16* __restrict__ H)
{
    int e = blockIdx.z;
    int m0 = blockIdx.y * 128;
    int c0 = blockIdx.x * 128;
    int ne = n_rows[e];
    if (m0 >= ne) return;
    __shared__ _Float16 Al[2][128 * 32];   // 16 KB
    __shared__ _Float16 Bl[3][256 * 32];   // 48 KB
    int tid = threadIdx.x;
    int lane = tid & 63, wave = tid >> 6;
    int r = lane & 15, q = lane >> 4;
    int wm = (wave & 1) * 64, wn = (wave >> 1) * 64;

    // Per-lane global src pointers, pre-swizzled so linear LDS dest == swizzled layout.
    // chunk ci = v*256 + tid; row = ci>>2; phys slot = ci&3; logical chunk = slot ^ ((row>>1)&3)
    const _Float16* agp[2];
    #pragma unroll
    for (int v = 0; v < 2; v++) {
        int ci = v * 256 + tid;
        int row = ci >> 2, slot = ci & 3;
        int c = slot ^ ((row >> 1) & 3);
        int token = (m0 + row < ne) ? row_token[e * CAP + m0 + row] : 0;
        agp[v] = xn16 + (size_t)token * DM + c * 8;
    }
    const _Float16* bgp[4];
    const _Float16* Wb = W12h + (size_t)e * (2 * DFF) * DM;
    #pragma unroll
    for (int v = 0; v < 4; v++) {
        int ci = v * 256 + tid;
        int row = ci >> 2, slot = ci & 3;
        int c = slot ^ ((row >> 1) & 3);
        int frow = (row < 128) ? (c0 + row) : (DFF + c0 + row - 128);
        bgp[v] = Wb + (size_t)frow * DM + c * 8;
    }

    #define STAGE_A1(k0, dst) do { \
        async16(agp[0] + (k0), (dst) + wave * 512); \
        async16(agp[1] + (k0), (dst) + 2048 + wave * 512); } while (0)
    #define STAGE_B1(k0, dst) do { \
        async16(bgp[0] + (k0), (dst) + wave * 512); \
        async16(bgp[1] + (k0), (dst) + 2048 + wave * 512); \
        async16(bgp[2] + (k0), (dst) + 4096 + wave * 512); \
        async16(bgp[3] + (k0), (dst) + 6144 + wave * 512); } while (0)

    // Prologue queue order must be [B0, A0, B1] so steady-state FIFO is
    // [B_t(4), A_t(2), B_{t+1}(4), A_{t+1}(2), B_{t+2}(4)] -> vmcnt(10) drains B_t+A_t.
    STAGE_B1(0, Bl[0]);
    STAGE_A1(0, Al[0]);
    STAGE_B1(32, Bl[1]);

    f32x4 accg[4][4] = {};
    f32x4 accu[4][4] = {};
    const int nt = DM / 32;   // 32
    int ia = 0, ib = 0;
    for (int t = 0; t < nt; ++t) {
        int k0 = t * 32;
        if (t + 1 < nt) STAGE_A1(k0 + 32, Al[ia ^ 1]);          // A_{t+1} -> other A buf
        if (t + 2 < nt) {                                        // B_{t+2} -> (ib+2)%3
            int ibn = (ib >= 1) ? ib - 1 : 2;
            STAGE_B1(k0 + 64, Bl[ibn]);
        }
        if (t + 2 < nt)      { VMCNT(10); }
        else if (t + 1 < nt) { VMCNT(6);  }
        else                 { VMCNT(0);  }
        BARRIER();   // all waves passed their vmcnt -> tile t fully in LDS

        const _Float16* Ab = Al[ia];
        const _Float16* Bb = Bl[ib];
        f16x8 a[4], bg[4], bu[4];
        #pragma unroll
        for (int i = 0; i < 4; i++) {
            int R = wm + i * 16 + r;
            int pc = q ^ ((R >> 1) & 3);
            a[i] = *(const f16x8*)(&Ab[R * 32 + pc * 8]);
        }
        #pragma unroll
        for (int j = 0; j < 4; j++) {
            int Rg = wn + j * 16 + r;
            int pcg = q ^ ((Rg >> 1) & 3);
            bg[j] = *(const f16x8*)(&Bb[Rg * 32 + pcg * 8]);
            int Ru = 128 + wn + j * 16 + r;
            int pcu = q ^ ((Ru >> 1) & 3);
            bu[j] = *(const f16x8*)(&Bb[Ru * 32 + pcu * 8]);
        }
        __builtin_amdgcn_s_setprio(1);
        #pragma unroll
        for (int i = 0; i < 4; i++) {
            #pragma unroll
            for (int j = 0; j < 4; j++) {
                accg[i][j] = __builtin_amdgcn_mfma_f32_16x16x32_f16(a[i], bg[j], accg[i][j], 0, 0, 0);
                accu[i][j] = __builtin_amdgcn_mfma_f32_16x16x32_f16(a[i], bu[j], accu[i][j], 0, 0, 0);
            }
        }
        __builtin_amdgcn_s_setprio(0);
        LGKM0();     // all ds_reads of this buffer complete before anyone restages it
        BARRIER();
        ia ^= 1;
        ib = (ib + 1 == 3) ? 0 : ib + 1;
    }
    #undef STAGE_A1
    #undef STAGE_B1

    // epilogue: h = silu(g) * u, store fp16
    #pragma unroll
    for (int i = 0; i < 4; i++) {
        #pragma unroll
        for (int j = 0; j < 4; j++) {
            #pragma unroll
            for (int g = 0; g < 4; g++) {
                int row = wm + i * 16 + q * 4 + g;
                int col = wn + j * 16 + r;
                float gv = accg[i][j][g], uv = accu[i][j][g];
                float h = gv / (1.0f + __expf(-gv)) * uv;
                H[((size_t)(e * CAP + m0 + row)) * DFF + c0 + col] = (_Float16)h;
            }
        }
    }
}

// ------- Kernel 4: GEMM2 (H @ W3h^T), counted-vmcnt ring pipeline, fused atomic combine -----
// BK=32, A ring-3 + B ring-3 (distance 2 both), 48 KB LDS, 2 blocks/CU.
__global__ __launch_bounds__(256, 2) void gemm2_kernel(
    const _Float16* __restrict__ H, const _Float16* __restrict__ W3h,
    const int* __restrict__ n_rows, const int* __restrict__ row_token,
    const float* __restrict__ row_w, float* __restrict__ out)
{
    int e = blockIdx.z;
    int m0 = blockIdx.y * 128;
    int c0 = blockIdx.x * 128;
    int ne = n_rows[e];
    if (m0 >= ne) return;
    __shared__ _Float16 Al[3][128 * 32];   // 24 KB
    __shared__ _Float16 Bl[3][128 * 32];   // 24 KB
    int tid = threadIdx.x;
    int lane = tid & 63, wave = tid >> 6;
    int r = lane & 15, q = lane >> 4;
    int wm = (wave & 1) * 64, wn = (wave >> 1) * 64;

    const _Float16* agp[2];
    const _Float16* Ab0 = H + ((size_t)(e * CAP + m0)) * DFF;
    #pragma unroll
    for (int v = 0; v < 2; v++) {
        int ci = v * 256 + tid;
        int row = ci >> 2, slot = ci & 3;
        int c = slot ^ ((row >> 1) & 3);
        agp[v] = Ab0 + (size_t)row * DFF + c * 8;
    }
    const _Float16* bgp[2];
    const _Float16* Wb = W3h + (size_t)e * DM * DFF;
    #pragma unroll
    for (int v = 0; v < 2; v++) {
        int ci = v * 256 + tid;
        int row = ci >> 2, slot = ci & 3;
        int c = slot ^ ((row >> 1) & 3);
        bgp[v] = Wb + (size_t)(c0 + row) * DFF + c * 8;
    }

    #define STAGE_A2(k0, dst) do { \
        async16(agp[0] + (k0), (dst) + wave * 512); \
        async16(agp[1] + (k0), (dst) + 2048 + wave * 512); } while (0)
    #define STAGE_B2(k0, dst) do { \
        async16(bgp[0] + (k0), (dst) + wave * 512); \
        async16(bgp[1] + (k0), (dst) + 2048 + wave * 512); } while (0)

    // prologue order [A0, B0, A1, B1]; steady FIFO [A_t,B_t,A_{t+1},B_{t+1},A_{t+2},B_{t+2}]
    STAGE_A2(0, Al[0]);
    STAGE_B2(0, Bl[0]);
    STAGE_A2(32, Al[1]);
    STAGE_B2(32, Bl[1]);

    f32x4 acc[4][4] = {};
    const int nt = DFF / 32;   // 128
    int ia = 0, ib = 0;
    for (int t = 0; t < nt; ++t) {
        int k0 = t * 32;
        if (t + 2 < nt) {
            int ian = (ia >= 1) ? ia - 1 : 2;
            STAGE_A2(k0 + 64, Al[ian]);
            int ibn = (ib >= 1) ? ib - 1 : 2;
            STAGE_B2(k0 + 64, Bl[ibn]);
            VMCNT(8);
        } else if (t + 1 < nt) {
            VMCNT(4);
        } else {
            VMCNT(0);
        }
        BARRIER();

        const _Float16* Ab = Al[ia];
        const _Float16* Bb = Bl[ib];
        f16x8 a[4], b[4];
        #pragma unroll
        for (int i = 0; i < 4; i++) {
            int R = wm + i * 16 + r;
            int pc = q ^ ((R >> 1) & 3);
            a[i] = *(const f16x8*)(&Ab[R * 32 + pc * 8]);
        }
        #pragma unroll
        for (int j = 0; j < 4; j++) {
            int R = wn + j * 16 + r;
            int pc = q ^ ((R >> 1) & 3);
            b[j] = *(const f16x8*)(&Bb[R * 32 + pc * 8]);
        }
        __builtin_amdgcn_s_setprio(1);
        #pragma unroll
        for (int i = 0; i < 4; i++) {
            #pragma unroll
            for (int j = 0; j < 4; j++)
                acc[i][j] = __builtin_amdgcn_mfma_f32_16x16x32_f16(a[i], b[j], acc[i][j], 0, 0, 0);
        }
        __builtin_amdgcn_s_setprio(0);
        LGKM0();
        BARRIER();
        ia = (ia + 1 == 3) ? 0 : ia + 1;
        ib = (ib + 1 == 3) ? 0 : ib + 1;
    }
    #undef STAGE_A2
    #undef STAGE_B2

    // epilogue: out[token] += w * y  (each out element touched by <= 2 slots)
    #pragma unroll
    for (int i = 0; i < 4; i++) {
        #pragma unroll
        for (int g = 0; g < 4; g++) {
            int m = m0 + wm + i * 16 + q * 4 + g;
            if (m < ne) {
                int dest = e * CAP + m;
                int tok = row_token[dest];
                float w = row_w[dest];
                #pragma unroll
                for (int j = 0; j < 4; j++) {
                    int col = c0 + wn + j * 16 + r;
                    atomicAdd(out + (size_t)tok * DM + col, w * acc[i][j][g]);
                }
            }
        }
    }
}

extern "C" void kernel_launch(void* const* d_in, const int* in_sizes, int n_in,
                              void* d_out, int out_size, void* d_ws, size_t ws_size,
                              hipStream_t stream) {
    const float* x     = (const float*)d_in[0];
    const float* gamma = (const float*)d_in[1];
    const float* beta  = (const float*)d_in[2];
    const float* Wr    = (const float*)d_in[3];
    const float* W12   = (const float*)d_in[4];
    const float* W3    = (const float*)d_in[5];
    float* out = (float*)d_out;
    char* ws = (char*)d_ws;

    _Float16* xn16    = (_Float16*)(ws);                 // 16,777,216 B
    _Float16* W12h    = (_Float16*)(ws + 16777216);      // 134,217,728 B
    _Float16* W3h     = (_Float16*)(ws + 150994944);     // 67,108,864 B
    _Float16* H       = (_Float16*)(ws + 218103808);     // 167,772,160 B
    int*      slot_e  = (int*)(ws + 385875968);          // 65,536 B
    float*    slot_w  = (float*)(ws + 385941504);        // 65,536 B
    int*      row_tok = (int*)(ws + 386007040);          // 81,920 B
    float*    row_w   = (float*)(ws + 386088960);        // 81,920 B
    int*      n_rows  = (int*)(ws + 386170880);          // 32 B

    hipMemsetAsync(d_out, 0, (size_t)out_size * sizeof(float), stream);

    hipLaunchKernelGGL(convert_kernel, dim3(4096), dim3(256), 0, stream,
                       W12, W12h, (NE * 2 * DFF * DM) / 4);
    hipLaunchKernelGGL(convert_kernel, dim3(2048), dim3(256), 0, stream,
                       W3, W3h, (NE * DM * DFF) / 4);
    hipLaunchKernelGGL(ln_router_kernel, dim3(T_TOKENS), dim3(256), 0, stream,
                       x, gamma, beta, Wr, xn16, slot_e, slot_w);
    hipLaunchKernelGGL(route_build_kernel, dim3(1), dim3(1024), 0, stream,
                       slot_e, slot_w, row_tok, row_w, n_rows);
    hipLaunchKernelGGL(gemm1_kernel, dim3(32, 20, NE), dim3(256), 0, stream,
                       xn16, W12h, n_rows, row_tok, H);
    hipLaunchKernelGGL(gemm2_kernel, dim3(8, 20, NE), dim3(256), 0, stream,
                       H, W3h, n_rows, row_tok, row_w, out);
}

// Round 2
// 1102.409 us; speedup vs baseline: 1.0416x; 1.0416x over previous
//
#include <hip/hip_runtime.h>

#define T_TOKENS 8192
#define DM 1024
#define DFF 4096
#define NE 8
#define CAP 2560

typedef _Float16 f16x8 __attribute__((ext_vector_type(8)));
typedef _Float16 f16x4 __attribute__((ext_vector_type(4)));
typedef float f32x4 __attribute__((ext_vector_type(4)));

#define VMCNT(n) asm volatile("s_waitcnt vmcnt(" #n ")" ::: "memory")
#define LGKM0()  asm volatile("s_waitcnt lgkmcnt(0)" ::: "memory")
#define BARRIER() do { __builtin_amdgcn_s_barrier(); __builtin_amdgcn_sched_barrier(0); } while (0)
#define WAITDS()  do { LGKM0(); __builtin_amdgcn_sched_barrier(0); } while (0)

__device__ __forceinline__ void async16(const _Float16* g, _Float16* l) {
    __builtin_amdgcn_global_load_lds(
        (const __attribute__((address_space(1))) void*)g,
        (__attribute__((address_space(3))) void*)l, 16, 0, 0);
}

// swizzled LDS fragment read: row stride 64 f16 (128B), phys 16B-chunk = lc ^ (row&7)
#define LDFRAG(buf, R, lc) (*(const f16x8*)&(buf)[(R) * 64 + (((lc) ^ ((R) & 7)) * 8)])

// ---------------- Kernel 0: fp32 -> fp16 weight convert ----------------
__global__ __launch_bounds__(256) void convert_kernel(
    const float* __restrict__ src, _Float16* __restrict__ dst, int n4)
{
    int i = blockIdx.x * blockDim.x + threadIdx.x;
    int stride = gridDim.x * blockDim.x;
    for (; i < n4; i += stride) {
        float4 v = ((const float4*)src)[i];
        f16x4 h = { (_Float16)v.x, (_Float16)v.y, (_Float16)v.z, (_Float16)v.w };
        ((f16x4*)dst)[i] = h;
    }
}

// ---------------- Kernel 1: LayerNorm + router (logits, softmax, top-2) ----------------
__global__ __launch_bounds__(256) void ln_router_kernel(
    const float* __restrict__ x, const float* __restrict__ gamma,
    const float* __restrict__ beta, const float* __restrict__ Wr,
    _Float16* __restrict__ xn16, int* __restrict__ slot_e, float* __restrict__ slot_w)
{
    int tok = blockIdx.x;
    int tid = threadIdx.x;
    int lane = tid & 63, wave = tid >> 6;
    const float* xr = x + (size_t)tok * DM + tid * 4;
    float4 xv = *(const float4*)xr;
    float s  = xv.x + xv.y + xv.z + xv.w;
    float ss = xv.x * xv.x + xv.y * xv.y + xv.z * xv.z + xv.w * xv.w;
    __shared__ float redS[4], redQ[4];
    __shared__ float l8s[4][NE];
    __shared__ float stats[2];
    #pragma unroll
    for (int o = 32; o > 0; o >>= 1) { s += __shfl_down(s, o); ss += __shfl_down(ss, o); }
    if (lane == 0) { redS[wave] = s; redQ[wave] = ss; }
    __syncthreads();
    if (tid == 0) {
        float S = redS[0] + redS[1] + redS[2] + redS[3];
        float Q = redQ[0] + redQ[1] + redQ[2] + redQ[3];
        float mu = S * (1.0f / DM);
        float var = Q * (1.0f / DM) - mu * mu;
        stats[0] = mu;
        stats[1] = rsqrtf(var + 1e-5f);
    }
    __syncthreads();
    float mu = stats[0], rstd = stats[1];
    float4 gv = *(const float4*)(gamma + tid * 4);
    float4 bv = *(const float4*)(beta + tid * 4);
    float xn0 = (xv.x - mu) * rstd * gv.x + bv.x;
    float xn1 = (xv.y - mu) * rstd * gv.y + bv.y;
    float xn2 = (xv.z - mu) * rstd * gv.z + bv.z;
    float xn3 = (xv.w - mu) * rstd * gv.w + bv.w;
    f16x4 h4 = { (_Float16)xn0, (_Float16)xn1, (_Float16)xn2, (_Float16)xn3 };
    *(f16x4*)(xn16 + (size_t)tok * DM + tid * 4) = h4;
    float l[NE];
    #pragma unroll
    for (int e = 0; e < NE; e++) {
        float4 wv = *(const float4*)(Wr + e * DM + tid * 4);
        l[e] = xn0 * wv.x + xn1 * wv.y + xn2 * wv.z + xn3 * wv.w;
    }
    #pragma unroll
    for (int e = 0; e < NE; e++) {
        #pragma unroll
        for (int o = 32; o > 0; o >>= 1) l[e] += __shfl_down(l[e], o);
    }
    if (lane == 0) {
        #pragma unroll
        for (int e = 0; e < NE; e++) l8s[wave][e] = l[e];
    }
    __syncthreads();
    if (tid == 0) {
        float lg[NE], ex[NE];
        float m = -1e30f;
        #pragma unroll
        for (int e = 0; e < NE; e++) {
            float v = l8s[0][e] + l8s[1][e] + l8s[2][e] + l8s[3][e];
            v = fminf(fmaxf(v, -10000.0f), 10000.0f);
            lg[e] = v;
            m = fmaxf(m, v);
        }
        float sum = 0.0f;
        #pragma unroll
        for (int e = 0; e < NE; e++) { ex[e] = expf(lg[e] - m); sum += ex[e]; }
        float inv = 1.0f / (sum + 1e-12f);
        int i0 = 0;
        #pragma unroll
        for (int e = 1; e < NE; e++) if (ex[e] > ex[i0]) i0 = e;
        int i1 = (i0 == 0) ? 1 : 0;
        #pragma unroll
        for (int e = 0; e < NE; e++) if (e != i0 && ex[e] > ex[i1]) i1 = e;
        slot_e[2 * tok]     = i0; slot_w[2 * tok]     = ex[i0] * inv;
        slot_e[2 * tok + 1] = i1; slot_w[2 * tok + 1] = ex[i1] * inv;
    }
}

// ------- Kernel 2: stable counting-sort routing: rank-within-expert + capacity drop -------
__global__ __launch_bounds__(1024) void route_build_kernel(
    const int* __restrict__ slot_e, const float* __restrict__ slot_w,
    int* __restrict__ row_token, float* __restrict__ row_w, int* __restrict__ n_rows)
{
    __shared__ int hist[1024][NE];
    int t = threadIdx.x;
    int cnt[NE];
    #pragma unroll
    for (int e = 0; e < NE; e++) cnt[e] = 0;
    int se[16];
    #pragma unroll
    for (int i = 0; i < 16; i++) { se[i] = slot_e[t * 16 + i]; cnt[se[i]]++; }
    #pragma unroll
    for (int e = 0; e < NE; e++) hist[t][e] = cnt[e];
    __syncthreads();
    for (int off = 1; off < 1024; off <<= 1) {
        int v[NE];
        bool has = (t >= off);
        if (has) {
            #pragma unroll
            for (int e = 0; e < NE; e++) v[e] = hist[t - off][e];
        }
        __syncthreads();
        if (has) {
            #pragma unroll
            for (int e = 0; e < NE; e++) hist[t][e] += v[e];
        }
        __syncthreads();
    }
    int run[NE];
    #pragma unroll
    for (int e = 0; e < NE; e++) run[e] = hist[t][e] - cnt[e];  // exclusive prefix
    if (t < NE) n_rows[t] = min(hist[1023][t], CAP);
    for (int i = 0; i < 16; i++) {
        int sidx = t * 16 + i;
        int e = se[i];
        int rnk = run[e]++;
        if (rnk < CAP) {
            int dest = e * CAP + rnk;
            row_token[dest] = sidx >> 1;
            row_w[dest] = slot_w[sidx];
        }
    }
}

// ===================== 8-phase K-loop (256-row x 256-Brow tile, BK=64) =====================
// 8 waves = 2M x 4N; per-wave output 128 rows x 64 B-rows; acc[8][4] (128 regs).
// Quadrants: Q1(m0-3,j0-1) Q2(m4-7,j0-1) Q3(m0-3,j2-3) Q4(m4-7,j2-3).
// A frags read p1/p2 and HELD in regs -> A buf restageable from p3. B read p1 (j0-1), p3 (j2-3).
// Stage slots: p1-2: B(odd tile, this iter) -> B1; p3-4: A(even+2) -> A0;
//              p5-6: B(even+2) -> B0;            p7-8: A(odd+2) -> A1.
// VMCNT(4) at p4 drains [A(odd), B(odd)] (needed p5); at p8 drains [A(e+2), B(e+2)] (next p1).
template<int NT>
__device__ __forceinline__ void kloop8(
    const _Float16* a0, const _Float16* a1, const _Float16* a2, const _Float16* a3,
    const _Float16* b0, const _Float16* b1, const _Float16* b2, const _Float16* b3,
    _Float16* A0, _Float16* A1, _Float16* B0, _Float16* B1,
    int wave, int wm, int wg, int r, int q, f32x4 (&acc)[8][4])
{
#define STGAH0(dst, k0) do { async16(a0 + (k0), (dst) + wave * 512); \
                             async16(a1 + (k0), (dst) + 4096 + wave * 512); } while (0)
#define STGAH1(dst, k0) do { async16(a2 + (k0), (dst) + 8192 + wave * 512); \
                             async16(a3 + (k0), (dst) + 12288 + wave * 512); } while (0)
#define STGBH0(dst, k0) do { async16(b0 + (k0), (dst) + wave * 512); \
                             async16(b1 + (k0), (dst) + 4096 + wave * 512); } while (0)
#define STGBH1(dst, k0) do { async16(b2 + (k0), (dst) + 8192 + wave * 512); \
                             async16(b3 + (k0), (dst) + 12288 + wave * 512); } while (0)
#define LOADA(buf, I0) \
    _Pragma("unroll") \
    for (int i = 0; i < 4; i++) { int R = wm + ((I0) + i) * 16 + r; \
        af[(I0) + i][0] = LDFRAG(buf, R, q); \
        af[(I0) + i][1] = LDFRAG(buf, R, 4 + q); }
#define LOADB(buf, J0) \
    _Pragma("unroll") \
    for (int j = 0; j < 2; j++) { int R = wg * 64 + ((J0) + j) * 16 + r; \
        bf[(J0) + j][0] = LDFRAG(buf, R, q); \
        bf[(J0) + j][1] = LDFRAG(buf, R, 4 + q); }
#define MMQ(I0, J0) do { \
    __builtin_amdgcn_s_setprio(1); \
    _Pragma("unroll") \
    for (int i = 0; i < 4; i++) \
        _Pragma("unroll") \
        for (int j = 0; j < 2; j++) \
            _Pragma("unroll") \
            for (int kf = 0; kf < 2; kf++) \
                acc[(I0) + i][(J0) + j] = __builtin_amdgcn_mfma_f32_16x16x32_f16( \
                    af[(I0) + i][kf], bf[(J0) + j][kf], acc[(I0) + i][(J0) + j], 0, 0, 0); \
    __builtin_amdgcn_s_setprio(0); } while (0)

    // prologue: issue order [A(0), B(0), A(1)]; vmcnt(4) drains A(0)+B(0), keeps A(1) in flight
    STGAH0(A0, 0);  STGAH1(A0, 0);
    STGBH0(B0, 0);  STGBH1(B0, 0);
    STGAH0(A1, 64); STGAH1(A1, 64);
    VMCNT(4);
    BARRIER();

    f16x8 af[8][2], bf[4][2];
    for (int t2 = 0; t2 < NT; t2 += 2) {
        const bool last = (t2 + 2 >= NT);
        const int kO = (t2 + 1) * 64, kN = (t2 + 2) * 64, kN1 = (t2 + 3) * 64;
        // ---------------- even tile (A0/B0) ----------------
        LOADA(A0, 0); LOADB(B0, 0);          // p1: 12 ds_read
        STGBH0(B1, kO);
        BARRIER(); WAITDS();
        MMQ(0, 0);
        BARRIER();

        LOADA(A0, 4);                         // p2: 8 ds_read -> A0 fully in regs
        STGBH1(B1, kO);
        BARRIER(); WAITDS();
        MMQ(4, 0);
        BARRIER();

        LOADB(B0, 2);                         // p3: 4 ds_read -> B0 fully in regs
        if (!last) STGAH0(A0, kN);
        BARRIER(); WAITDS();
        MMQ(0, 2);
        BARRIER();

        if (!last) { STGAH1(A0, kN); VMCNT(4); } else { VMCNT(0); }   // p4
        BARRIER();
        MMQ(4, 2);
        BARRIER();
        // ---------------- odd tile (A1/B1) ----------------
        LOADA(A1, 0); LOADB(B1, 0);          // p5
        if (!last) STGBH0(B0, kN);
        BARRIER(); WAITDS();
        MMQ(0, 0);
        BARRIER();

        LOADA(A1, 4);                         // p6
        if (!last) STGBH1(B0, kN);
        BARRIER(); WAITDS();
        MMQ(4, 0);
        BARRIER();

        LOADB(B1, 2);                         // p7
        if (!last) STGAH0(A1, kN1);
        BARRIER(); WAITDS();
        MMQ(0, 2);
        BARRIER();

        if (!last) { STGAH1(A1, kN1); VMCNT(4); } else { VMCNT(0); }  // p8
        BARRIER();
        MMQ(4, 2);
        BARRIER();
    }
#undef STGAH0
#undef STGAH1
#undef STGBH0
#undef STGBH1
#undef LOADA
#undef LOADB
#undef MMQ
}

// ------- Kernel 3: GEMM1, 8-phase 256x(128f g+u) tile, fused SiLU*u (in-register pairing) ----
// B-tile rows: per 32-f group g: [32 g-rows; 32 u-rows] -> thread's j0,1 (g) and j2,3 (u)
// carry the SAME f-column, so SiLU fusion needs no LDS exchange.
__global__ __launch_bounds__(512, 2) void gemm1_kernel(
    const _Float16* __restrict__ xn16, const _Float16* __restrict__ W12h,
    const int* __restrict__ n_rows, const int* __restrict__ row_token,
    _Float16* __restrict__ H)
{
    int e = blockIdx.z;
    int m0 = blockIdx.y * 256;
    int c0 = blockIdx.x * 128;
    int ne = n_rows[e];
    if (m0 >= ne) return;
    __shared__ _Float16 A0[256 * 64], A1[256 * 64], B0[256 * 64], B1[256 * 64]; // 128 KiB
    int tid = threadIdx.x;
    int lane = tid & 63, wave = tid >> 6;
    int r = lane & 15, q = lane >> 4;
    int wm = (wave & 1) * 128;
    int wg = wave >> 1;

    // staging: chunk ci = v*512 + tid; row = ci>>3; phys slot = ci&7; logical chunk = slot^(row&7)
    const _Float16* agp[4];
    #pragma unroll
    for (int v = 0; v < 4; v++) {
        int ci = v * 512 + tid;
        int row = ci >> 3, slot = ci & 7;
        int c = slot ^ (row & 7);
        int token = (m0 + row < ne) ? row_token[e * CAP + m0 + row] : 0;
        agp[v] = xn16 + (size_t)token * DM + c * 8;
    }
    const _Float16* bgp[4];
    const _Float16* Wb = W12h + (size_t)e * (2 * DFF) * DM;
    #pragma unroll
    for (int v = 0; v < 4; v++) {
        int ci = v * 512 + tid;
        int row = ci >> 3, slot = ci & 7;
        int c = slot ^ (row & 7);
        int grp = row >> 6, within = row & 63;
        int frow = (within < 32) ? (c0 + grp * 32 + within)
                                 : (DFF + c0 + grp * 32 + within - 32);
        bgp[v] = Wb + (size_t)frow * DM + c * 8;
    }

    f32x4 acc[8][4] = {};
    kloop8<DM / 64>(agp[0], agp[1], agp[2], agp[3], bgp[0], bgp[1], bgp[2], bgp[3],
                    A0, A1, B0, B1, wave, wm, wg, r, q, acc);

    // epilogue: h = silu(g) * u (g = acc[i][jj], u = acc[i][jj+2], same f), store fp16
    #pragma unroll
    for (int i = 0; i < 8; i++) {
        #pragma unroll
        for (int jj = 0; jj < 2; jj++) {
            int f = c0 + wg * 32 + jj * 16 + r;
            #pragma unroll
            for (int gi = 0; gi < 4; gi++) {
                int row = wm + i * 16 + q * 4 + gi;
                float gv = acc[i][jj][gi], uv = acc[i][jj + 2][gi];
                float h = gv / (1.0f + __expf(-gv)) * uv;
                H[((size_t)(e * CAP + m0 + row)) * DFF + f] = (_Float16)h;
            }
        }
    }
}

// ------- Kernel 4: GEMM2 (H @ W3h^T), round-0 structure (128x128, global_load_lds, 2-phase) ---
__global__ __launch_bounds__(256, 2) void gemm2_kernel(
    const _Float16* __restrict__ H, const _Float16* __restrict__ W3h,
    const int* __restrict__ n_rows, const int* __restrict__ row_token,
    const float* __restrict__ row_w, float* __restrict__ out)
{
    int e = blockIdx.z;
    int m0 = blockIdx.y * 128;
    int c0 = blockIdx.x * 128;
    int ne = n_rows[e];
    if (m0 >= ne) return;
    __shared__ _Float16 Al[128 * 64];
    __shared__ _Float16 Bl[128 * 64];
    int tid = threadIdx.x;
    int lane = tid & 63, wave = tid >> 6;
    int r = lane & 15, q = lane >> 4;
    int wm = (wave & 1) * 64, wn = (wave >> 1) * 64;

    const _Float16* agp[4];
    const _Float16* Ab = H + ((size_t)(e * CAP + m0)) * DFF;
    #pragma unroll
    for (int v = 0; v < 4; v++) {
        int ci = v * 256 + tid;
        int row = ci >> 3, slot = ci & 7;
        int c = slot ^ (row & 7);
        agp[v] = Ab + (size_t)row * DFF + c * 8;
    }
    const _Float16* bgp[4];
    const _Float16* Wb = W3h + (size_t)e * DM * DFF;
    #pragma unroll
    for (int v = 0; v < 4; v++) {
        int ci = v * 256 + tid;
        int row = ci >> 3, slot = ci & 7;
        int c = slot ^ (row & 7);
        bgp[v] = Wb + (size_t)(c0 + row) * DFF + c * 8;
    }

    f32x4 acc[4][4] = {};
    for (int k0 = 0; k0 < DFF; k0 += 64) {
        #pragma unroll
        for (int v = 0; v < 4; v++)
            async16(agp[v] + k0, Al + v * 2048 + (tid >> 6) * 512);
        #pragma unroll
        for (int v = 0; v < 4; v++)
            async16(bgp[v] + k0, Bl + v * 2048 + (tid >> 6) * 512);
        __syncthreads();
        #pragma unroll
        for (int kf = 0; kf < 2; kf++) {
            f16x8 a[4], b[4];
            #pragma unroll
            for (int i = 0; i < 4; i++) {
                int R = wm + i * 16 + r;
                int pc = (kf * 4 + q) ^ (R & 7);
                a[i] = *(const f16x8*)(&Al[R * 64 + pc * 8]);
            }
            #pragma unroll
            for (int j = 0; j < 4; j++) {
                int R = wn + j * 16 + r;
                int pc = (kf * 4 + q) ^ (R & 7);
                b[j] = *(const f16x8*)(&Bl[R * 64 + pc * 8]);
            }
            #pragma unroll
            for (int i = 0; i < 4; i++) {
                #pragma unroll
                for (int j = 0; j < 4; j++)
                    acc[i][j] = __builtin_amdgcn_mfma_f32_16x16x32_f16(a[i], b[j], acc[i][j], 0, 0, 0);
            }
        }
        __syncthreads();
    }
    // epilogue: out[token] += w * y  (each out element touched by <= 2 slots)
    #pragma unroll
    for (int i = 0; i < 4; i++) {
        #pragma unroll
        for (int g = 0; g < 4; g++) {
            int m = m0 + wm + i * 16 + q * 4 + g;
            if (m < ne) {
                int dest = e * CAP + m;
                int tok = row_token[dest];
                float w = row_w[dest];
                #pragma unroll
                for (int j = 0; j < 4; j++) {
                    int col = c0 + wn + j * 16 + r;
                    atomicAdd(out + (size_t)tok * DM + col, w * acc[i][j][g]);
                }
            }
        }
    }
}

extern "C" void kernel_launch(void* const* d_in, const int* in_sizes, int n_in,
                              void* d_out, int out_size, void* d_ws, size_t ws_size,
                              hipStream_t stream) {
    const float* x     = (const float*)d_in[0];
    const float* gamma = (const float*)d_in[1];
    const float* beta  = (const float*)d_in[2];
    const float* Wr    = (const float*)d_in[3];
    const float* W12   = (const float*)d_in[4];
    const float* W3    = (const float*)d_in[5];
    float* out = (float*)d_out;
    char* ws = (char*)d_ws;

    _Float16* xn16    = (_Float16*)(ws);                 // 16,777,216 B
    _Float16* W12h    = (_Float16*)(ws + 16777216);      // 134,217,728 B
    _Float16* W3h     = (_Float16*)(ws + 150994944);     // 67,108,864 B
    _Float16* H       = (_Float16*)(ws + 218103808);     // 167,772,160 B
    int*      slot_e  = (int*)(ws + 385875968);          // 65,536 B
    float*    slot_w  = (float*)(ws + 385941504);        // 65,536 B
    int*      row_tok = (int*)(ws + 386007040);          // 81,920 B
    float*    row_w   = (float*)(ws + 386088960);        // 81,920 B
    int*      n_rows  = (int*)(ws + 386170880);          // 32 B

    hipMemsetAsync(d_out, 0, (size_t)out_size * sizeof(float), stream);

    hipLaunchKernelGGL(convert_kernel, dim3(4096), dim3(256), 0, stream,
                       W12, W12h, (NE * 2 * DFF * DM) / 4);
    hipLaunchKernelGGL(convert_kernel, dim3(2048), dim3(256), 0, stream,
                       W3, W3h, (NE * DM * DFF) / 4);
    hipLaunchKernelGGL(ln_router_kernel, dim3(T_TOKENS), dim3(256), 0, stream,
                       x, gamma, beta, Wr, xn16, slot_e, slot_w);
    hipLaunchKernelGGL(route_build_kernel, dim3(1), dim3(1024), 0, stream,
                       slot_e, slot_w, row_tok, row_w, n_rows);
    hipLaunchKernelGGL(gemm1_kernel, dim3(DFF / 128, 10, NE), dim3(512), 0, stream,
                       xn16, W12h, n_rows, row_tok, H);
    hipLaunchKernelGGL(gemm2_kernel, dim3(8, 20, NE), dim3(256), 0, stream,
                       H, W3h, n_rows, row_tok, row_w, out);
}

// Round 3
// 1070.209 us; speedup vs baseline: 1.0729x; 1.0301x over previous
//
#include <hip/hip_runtime.h>

#define T_TOKENS 8192
#define DM 1024
#define DFF 4096
#define NE 8
#define CAP 2560

typedef _Float16 f16x8 __attribute__((ext_vector_type(8)));
typedef _Float16 f16x4 __attribute__((ext_vector_type(4)));
typedef float f32x4 __attribute__((ext_vector_type(4)));

__device__ __forceinline__ void async16(const _Float16* g, _Float16* l) {
    __builtin_amdgcn_global_load_lds(
        (const __attribute__((address_space(1))) void*)g,
        (__attribute__((address_space(3))) void*)l, 16, 0, 0);
}

// ---------------- Kernel 0: fp32 -> fp16 weight convert ----------------
__global__ __launch_bounds__(256) void convert_kernel(
    const float* __restrict__ src, _Float16* __restrict__ dst, int n4)
{
    int i = blockIdx.x * blockDim.x + threadIdx.x;
    int stride = gridDim.x * blockDim.x;
    for (; i < n4; i += stride) {
        float4 v = ((const float4*)src)[i];
        f16x4 h = { (_Float16)v.x, (_Float16)v.y, (_Float16)v.z, (_Float16)v.w };
        ((f16x4*)dst)[i] = h;
    }
}

// ---------------- Kernel 1: LayerNorm + router (logits, softmax, top-2) ----------------
__global__ __launch_bounds__(256) void ln_router_kernel(
    const float* __restrict__ x, const float* __restrict__ gamma,
    const float* __restrict__ beta, const float* __restrict__ Wr,
    _Float16* __restrict__ xn16, int* __restrict__ slot_e, float* __restrict__ slot_w)
{
    int tok = blockIdx.x;
    int tid = threadIdx.x;
    int lane = tid & 63, wave = tid >> 6;
    const float* xr = x + (size_t)tok * DM + tid * 4;
    float4 xv = *(const float4*)xr;
    float s  = xv.x + xv.y + xv.z + xv.w;
    float ss = xv.x * xv.x + xv.y * xv.y + xv.z * xv.z + xv.w * xv.w;
    __shared__ float redS[4], redQ[4];
    __shared__ float l8s[4][NE];
    __shared__ float stats[2];
    #pragma unroll
    for (int o = 32; o > 0; o >>= 1) { s += __shfl_down(s, o); ss += __shfl_down(ss, o); }
    if (lane == 0) { redS[wave] = s; redQ[wave] = ss; }
    __syncthreads();
    if (tid == 0) {
        float S = redS[0] + redS[1] + redS[2] + redS[3];
        float Q = redQ[0] + redQ[1] + redQ[2] + redQ[3];
        float mu = S * (1.0f / DM);
        float var = Q * (1.0f / DM) - mu * mu;
        stats[0] = mu;
        stats[1] = rsqrtf(var + 1e-5f);
    }
    __syncthreads();
    float mu = stats[0], rstd = stats[1];
    float4 gv = *(const float4*)(gamma + tid * 4);
    float4 bv = *(const float4*)(beta + tid * 4);
    float xn0 = (xv.x - mu) * rstd * gv.x + bv.x;
    float xn1 = (xv.y - mu) * rstd * gv.y + bv.y;
    float xn2 = (xv.z - mu) * rstd * gv.z + bv.z;
    float xn3 = (xv.w - mu) * rstd * gv.w + bv.w;
    f16x4 h4 = { (_Float16)xn0, (_Float16)xn1, (_Float16)xn2, (_Float16)xn3 };
    *(f16x4*)(xn16 + (size_t)tok * DM + tid * 4) = h4;
    float l[NE];
    #pragma unroll
    for (int e = 0; e < NE; e++) {
        float4 wv = *(const float4*)(Wr + e * DM + tid * 4);
        l[e] = xn0 * wv.x + xn1 * wv.y + xn2 * wv.z + xn3 * wv.w;
    }
    #pragma unroll
    for (int e = 0; e < NE; e++) {
        #pragma unroll
        for (int o = 32; o > 0; o >>= 1) l[e] += __shfl_down(l[e], o);
    }
    if (lane == 0) {
        #pragma unroll
        for (int e = 0; e < NE; e++) l8s[wave][e] = l[e];
    }
    __syncthreads();
    if (tid == 0) {
        float lg[NE], ex[NE];
        float m = -1e30f;
        #pragma unroll
        for (int e = 0; e < NE; e++) {
            float v = l8s[0][e] + l8s[1][e] + l8s[2][e] + l8s[3][e];
            v = fminf(fmaxf(v, -10000.0f), 10000.0f);
            lg[e] = v;
            m = fmaxf(m, v);
        }
        float sum = 0.0f;
        #pragma unroll
        for (int e = 0; e < NE; e++) { ex[e] = expf(lg[e] - m); sum += ex[e]; }
        float inv = 1.0f / (sum + 1e-12f);
        int i0 = 0;
        #pragma unroll
        for (int e = 1; e < NE; e++) if (ex[e] > ex[i0]) i0 = e;
        int i1 = (i0 == 0) ? 1 : 0;
        #pragma unroll
        for (int e = 0; e < NE; e++) if (e != i0 && ex[e] > ex[i1]) i1 = e;
        slot_e[2 * tok]     = i0; slot_w[2 * tok]     = ex[i0] * inv;
        slot_e[2 * tok + 1] = i1; slot_w[2 * tok + 1] = ex[i1] * inv;
    }
}

// ------- Kernel 2: stable counting-sort routing: rank-within-expert + capacity drop -------
// Also emits inv_slot[sidx] = dest slot (or -1 if dropped). inv_slot may ALIAS slot_e:
// all slot_e reads are register-cached (se[]) before the scan's barriers; inv_slot writes
// happen after the final barrier, so the aliasing is race-free.
__global__ __launch_bounds__(1024) void route_build_kernel(
    const int* __restrict__ slot_e, const float* __restrict__ slot_w,
    int* __restrict__ row_token, float* __restrict__ row_w, int* __restrict__ n_rows,
    int* __restrict__ inv_slot)
{
    __shared__ int hist[1024][NE];
    int t = threadIdx.x;
    int cnt[NE];
    #pragma unroll
    for (int e = 0; e < NE; e++) cnt[e] = 0;
    int se[16];
    #pragma unroll
    for (int i = 0; i < 16; i++) { se[i] = slot_e[t * 16 + i]; cnt[se[i]]++; }
    #pragma unroll
    for (int e = 0; e < NE; e++) hist[t][e] = cnt[e];
    __syncthreads();
    for (int off = 1; off < 1024; off <<= 1) {
        int v[NE];
        bool has = (t >= off);
        if (has) {
            #pragma unroll
            for (int e = 0; e < NE; e++) v[e] = hist[t - off][e];
        }
        __syncthreads();
        if (has) {
            #pragma unroll
            for (int e = 0; e < NE; e++) hist[t][e] += v[e];
        }
        __syncthreads();
    }
    int run[NE];
    #pragma unroll
    for (int e = 0; e < NE; e++) run[e] = hist[t][e] - cnt[e];  // exclusive prefix
    if (t < NE) n_rows[t] = min(hist[1023][t], CAP);
    for (int i = 0; i < 16; i++) {
        int sidx = t * 16 + i;
        int e = se[i];
        int rnk = run[e]++;
        if (rnk < CAP) {
            int dest = e * CAP + rnk;
            row_token[dest] = sidx >> 1;
            row_w[dest] = slot_w[sidx];
            inv_slot[sidx] = dest;
        } else {
            inv_slot[sidx] = -1;
        }
    }
}

// ------- Kernel 3: GEMM1 (gathered xn @ W12h^T), global_load_lds staging, fused SiLU*u -------
// block tile: 128 rows x (128 g-cols + 128 u-cols). XOR-swizzled LDS, unpadded 128B rows.
__global__ __launch_bounds__(256, 2) void gemm1_kernel(
    const _Float16* __restrict__ xn16, const _Float16* __restrict__ W12h,
    const int* __restrict__ n_rows, const int* __restrict__ row_token,
    _Float16* __restrict__ H)
{
    int e = blockIdx.z;
    int m0 = blockIdx.y * 128;
    int c0 = blockIdx.x * 128;
    int ne = n_rows[e];
    if (m0 >= ne) return;
    __shared__ _Float16 Al[128 * 64];
    __shared__ _Float16 Bl[256 * 64];
    int tid = threadIdx.x;
    int lane = tid & 63, wave = tid >> 6;
    int r = lane & 15, q = lane >> 4;
    int wm = (wave & 1) * 64, wn = (wave >> 1) * 64;

    // Precompute per-issue global base pointers (k-independent).
    // chunk ci = v*256 + tid; row = ci>>3; phys slot = ci&7; logical chunk = slot ^ (row&7)
    const _Float16* agp[4];
    #pragma unroll
    for (int v = 0; v < 4; v++) {
        int ci = v * 256 + tid;
        int row = ci >> 3, slot = ci & 7;
        int c = slot ^ (row & 7);
        int token = (m0 + row < ne) ? row_token[e * CAP + m0 + row] : 0;
        agp[v] = xn16 + (size_t)token * DM + c * 8;
    }
    const _Float16* bgp[8];
    const _Float16* Wb = W12h + (size_t)e * (2 * DFF) * DM;
    #pragma unroll
    for (int v = 0; v < 8; v++) {
        int ci = v * 256 + tid;
        int row = ci >> 3, slot = ci & 7;
        int c = slot ^ (row & 7);
        int frow = (row < 128) ? (c0 + row) : (DFF + c0 + row - 128);
        bgp[v] = Wb + (size_t)frow * DM + c * 8;
    }

    f32x4 accg[4][4] = {};
    f32x4 accu[4][4] = {};
    for (int k0 = 0; k0 < DM; k0 += 64) {
        #pragma unroll
        for (int v = 0; v < 4; v++)
            async16(agp[v] + k0, Al + v * 2048 + (tid >> 6) * 512);
        #pragma unroll
        for (int v = 0; v < 8; v++)
            async16(bgp[v] + k0, Bl + v * 2048 + (tid >> 6) * 512);
        __syncthreads();
        #pragma unroll
        for (int kf = 0; kf < 2; kf++) {
            f16x8 a[4], bg[4], bu[4];
            #pragma unroll
            for (int i = 0; i < 4; i++) {
                int R = wm + i * 16 + r;
                int pc = (kf * 4 + q) ^ (R & 7);
                a[i] = *(const f16x8*)(&Al[R * 64 + pc * 8]);
            }
            #pragma unroll
            for (int j = 0; j < 4; j++) {
                int Rg = wn + j * 16 + r;
                int pcg = (kf * 4 + q) ^ (Rg & 7);
                bg[j] = *(const f16x8*)(&Bl[Rg * 64 + pcg * 8]);
                int Ru = 128 + wn + j * 16 + r;
                int pcu = (kf * 4 + q) ^ (Ru & 7);
                bu[j] = *(const f16x8*)(&Bl[Ru * 64 + pcu * 8]);
            }
            #pragma unroll
            for (int i = 0; i < 4; i++) {
                #pragma unroll
                for (int j = 0; j < 4; j++) {
                    accg[i][j] = __builtin_amdgcn_mfma_f32_16x16x32_f16(a[i], bg[j], accg[i][j], 0, 0, 0);
                    accu[i][j] = __builtin_amdgcn_mfma_f32_16x16x32_f16(a[i], bu[j], accu[i][j], 0, 0, 0);
                }
            }
        }
        __syncthreads();
    }
    // epilogue: h = silu(g) * u, store fp16
    #pragma unroll
    for (int i = 0; i < 4; i++) {
        #pragma unroll
        for (int j = 0; j < 4; j++) {
            #pragma unroll
            for (int g = 0; g < 4; g++) {
                int row = wm + i * 16 + q * 4 + g;
                int col = wn + j * 16 + r;
                float gv = accg[i][j][g], uv = accu[i][j][g];
                float h = gv / (1.0f + __expf(-gv)) * uv;
                H[((size_t)(e * CAP + m0 + row)) * DFF + c0 + col] = (_Float16)h;
            }
        }
    }
}

// ------- Kernel 4: GEMM2 (H @ W3h^T), global_load_lds staging, NON-ATOMIC slot writes -------
// Writes w * y rows to y_slot[e*CAP+m][DM] (streaming f32 stores). Combine kernel gathers.
__global__ __launch_bounds__(256, 2) void gemm2_kernel(
    const _Float16* __restrict__ H, const _Float16* __restrict__ W3h,
    const int* __restrict__ n_rows, const float* __restrict__ row_w,
    float* __restrict__ y_slot)
{
    int e = blockIdx.z;
    int m0 = blockIdx.y * 128;
    int c0 = blockIdx.x * 128;
    int ne = n_rows[e];
    if (m0 >= ne) return;
    __shared__ _Float16 Al[128 * 64];
    __shared__ _Float16 Bl[128 * 64];
    int tid = threadIdx.x;
    int lane = tid & 63, wave = tid >> 6;
    int r = lane & 15, q = lane >> 4;
    int wm = (wave & 1) * 64, wn = (wave >> 1) * 64;

    const _Float16* agp[4];
    const _Float16* Ab = H + ((size_t)(e * CAP + m0)) * DFF;
    #pragma unroll
    for (int v = 0; v < 4; v++) {
        int ci = v * 256 + tid;
        int row = ci >> 3, slot = ci & 7;
        int c = slot ^ (row & 7);
        agp[v] = Ab + (size_t)row * DFF + c * 8;
    }
    const _Float16* bgp[4];
    const _Float16* Wb = W3h + (size_t)e * DM * DFF;
    #pragma unroll
    for (int v = 0; v < 4; v++) {
        int ci = v * 256 + tid;
        int row = ci >> 3, slot = ci & 7;
        int c = slot ^ (row & 7);
        bgp[v] = Wb + (size_t)(c0 + row) * DFF + c * 8;
    }

    f32x4 acc[4][4] = {};
    for (int k0 = 0; k0 < DFF; k0 += 64) {
        #pragma unroll
        for (int v = 0; v < 4; v++)
            async16(agp[v] + k0, Al + v * 2048 + (tid >> 6) * 512);
        #pragma unroll
        for (int v = 0; v < 4; v++)
            async16(bgp[v] + k0, Bl + v * 2048 + (tid >> 6) * 512);
        __syncthreads();
        #pragma unroll
        for (int kf = 0; kf < 2; kf++) {
            f16x8 a[4], b[4];
            #pragma unroll
            for (int i = 0; i < 4; i++) {
                int R = wm + i * 16 + r;
                int pc = (kf * 4 + q) ^ (R & 7);
                a[i] = *(const f16x8*)(&Al[R * 64 + pc * 8]);
            }
            #pragma unroll
            for (int j = 0; j < 4; j++) {
                int R = wn + j * 16 + r;
                int pc = (kf * 4 + q) ^ (R & 7);
                b[j] = *(const f16x8*)(&Bl[R * 64 + pc * 8]);
            }
            #pragma unroll
            for (int i = 0; i < 4; i++) {
                #pragma unroll
                for (int j = 0; j < 4; j++)
                    acc[i][j] = __builtin_amdgcn_mfma_f32_16x16x32_f16(a[i], b[j], acc[i][j], 0, 0, 0);
            }
        }
        __syncthreads();
    }
    // epilogue: y_slot[dest] = w * y  (plain streaming stores, no atomics)
    #pragma unroll
    for (int i = 0; i < 4; i++) {
        #pragma unroll
        for (int g = 0; g < 4; g++) {
            int m = m0 + wm + i * 16 + q * 4 + g;
            if (m < ne) {
                int dest = e * CAP + m;
                float w = row_w[dest];
                #pragma unroll
                for (int j = 0; j < 4; j++) {
                    int col = c0 + wn + j * 16 + r;
                    y_slot[(size_t)dest * DM + col] = w * acc[i][j][g];
                }
            }
        }
    }
}

// ------- Kernel 5: combine — out[t] = y_slot[s0] + y_slot[s1] (s = inv_slot, -1 = dropped) ---
__global__ __launch_bounds__(256) void combine_kernel(
    const float* __restrict__ y_slot, const int* __restrict__ inv_slot,
    float* __restrict__ out)
{
    int t = blockIdx.x;
    int tid = threadIdx.x;
    int s0 = inv_slot[2 * t];
    int s1 = inv_slot[2 * t + 1];
    f32x4 acc = {0.0f, 0.0f, 0.0f, 0.0f};
    if (s0 >= 0) {
        f32x4 v = *(const f32x4*)(y_slot + (size_t)s0 * DM + tid * 4);
        acc = v;
    }
    if (s1 >= 0) {
        f32x4 v = *(const f32x4*)(y_slot + (size_t)s1 * DM + tid * 4);
        acc[0] += v[0]; acc[1] += v[1]; acc[2] += v[2]; acc[3] += v[3];
    }
    *(f32x4*)(out + (size_t)t * DM + tid * 4) = acc;
}

extern "C" void kernel_launch(void* const* d_in, const int* in_sizes, int n_in,
                              void* d_out, int out_size, void* d_ws, size_t ws_size,
                              hipStream_t stream) {
    const float* x     = (const float*)d_in[0];
    const float* gamma = (const float*)d_in[1];
    const float* beta  = (const float*)d_in[2];
    const float* Wr    = (const float*)d_in[3];
    const float* W12   = (const float*)d_in[4];
    const float* W3    = (const float*)d_in[5];
    float* out = (float*)d_out;
    char* ws = (char*)d_ws;

    _Float16* xn16    = (_Float16*)(ws);                 // 16,777,216 B
    _Float16* W12h    = (_Float16*)(ws + 16777216);      // 134,217,728 B  (dead after gemm1)
    _Float16* W3h     = (_Float16*)(ws + 150994944);     // 67,108,864 B
    _Float16* H       = (_Float16*)(ws + 218103808);     // 167,772,160 B
    int*      slot_e  = (int*)(ws + 385875968);          // 65,536 B (reused as inv_slot)
    float*    slot_w  = (float*)(ws + 385941504);        // 65,536 B
    int*      row_tok = (int*)(ws + 386007040);          // 81,920 B
    float*    row_w   = (float*)(ws + 386088960);        // 81,920 B
    int*      n_rows  = (int*)(ws + 386170880);          // 32 B

    // y_slot (E*CAP*DM f32 = 83,886,080 B) lives in the W12h region: W12h is only read by
    // gemm1, which completes before gemm2 writes y_slot. inv_slot aliases slot_e (see
    // route_build_kernel comment).
    float* y_slot   = (float*)(ws + 16777216);
    int*   inv_slot = slot_e;

    hipLaunchKernelGGL(convert_kernel, dim3(4096), dim3(256), 0, stream,
                       W12, W12h, (NE * 2 * DFF * DM) / 4);
    hipLaunchKernelGGL(convert_kernel, dim3(2048), dim3(256), 0, stream,
                       W3, W3h, (NE * DM * DFF) / 4);
    hipLaunchKernelGGL(ln_router_kernel, dim3(T_TOKENS), dim3(256), 0, stream,
                       x, gamma, beta, Wr, xn16, slot_e, slot_w);
    hipLaunchKernelGGL(route_build_kernel, dim3(1), dim3(1024), 0, stream,
                       slot_e, slot_w, row_tok, row_w, n_rows, inv_slot);
    hipLaunchKernelGGL(gemm1_kernel, dim3(32, 20, NE), dim3(256), 0, stream,
                       xn16, W12h, n_rows, row_tok, H);
    hipLaunchKernelGGL(gemm2_kernel, dim3(8, 20, NE), dim3(256), 0, stream,
                       H, W3h, n_rows, row_w, y_slot);
    hipLaunchKernelGGL(combine_kernel, dim3(T_TOKENS), dim3(256), 0, stream,
                       y_slot, inv_slot, out);
}